// Round 22
// baseline (1557.557 us; speedup 1.0000x reference)
//
#include <hip/hip_runtime.h>

// Problem constants (fixed by reference setup_inputs)
#define N_NODES  65536
#define D_FEAT   256
#define N_GRAPHS 256
#define NPG      256
#define N_EDGES  524288
#define CAPX     2560     // support cap (true max = 2048 edges + 256 diag = 2304)
#define EPSF     0.1f
#define MAXIT    100
#define KROW     12       // register slots per row (single-wave sink); overflow -> LDS
#define LOG2E_F  1.4426950408889634f
#define LN2_F    0.6931471805599453f
#define CSCALE   (10.0f * LOG2E_F)   // C * (1/eps) * log2(e) -> base-2 domain
#define MU_VAL   (1.0f / 256.0f + 1e-8f)

// dynamic LDS region (131072 B), time-multiplexed:
//   phase A: m (8 KB) + mT (8 KB) + rowpref (8 KB)
//   phase B/C: tgtb = 256 rows x 512 B bf16, 6-bit XOR granule swizzle (R20)
//   epilogue: strip = 128 rows x 256 f32
#define DYN_SIZE  131072

typedef __attribute__((ext_vector_type(8))) short short8;
typedef __attribute__((ext_vector_type(4))) float f32x4;
union U8 { unsigned u[4]; short8 v; };

template<int CTRL>
__device__ __forceinline__ float fdpp(float x){
  int xi = __float_as_int(x);
  int i = __builtin_amdgcn_update_dpp(xi, xi, CTRL, 0xf, 0xf, true);
  return __int_as_float(i);
}
__device__ __forceinline__ float dppSum64(float x){
  x += fdpp<0x111>(x);
  x += fdpp<0x112>(x);
  x += fdpp<0x114>(x);
  x += fdpp<0x118>(x);
  x += fdpp<0x142>(x);
  x += fdpp<0x143>(x);
  return x;
}
__device__ __forceinline__ float bcast63(float x){
  return __int_as_float(__builtin_amdgcn_readlane(__float_as_int(x), 63));
}

// int DPP with old=0 — for masked scan steps
template<int CTRL, int RMASK>
__device__ __forceinline__ int idpp0(int x){
  return __builtin_amdgcn_update_dpp(0, x, CTRL, RMASK, 0xf, true);
}
__device__ __forceinline__ int dppScanAdd64(int x){
  x += idpp0<0x111, 0xf>(x);
  x += idpp0<0x112, 0xf>(x);
  x += idpp0<0x114, 0xf>(x);
  x += idpp0<0x118, 0xf>(x);
  x += idpp0<0x142, 0xa>(x);
  x += idpp0<0x143, 0xc>(x);
  return x;
}

__device__ __forceinline__ unsigned bf16r(float f){
  unsigned u = __float_as_uint(f);
  return (u + 0x7FFFu + ((u >> 16) & 1u)) >> 16;
}

// -------- scatter edges + diagonal into per-graph bitmask --------
__global__ __launch_bounds__(256) void k_scatter(const int* __restrict__ ei,
                                                 unsigned* __restrict__ bm){
  int t = blockIdx.x * 256 + threadIdx.x;
  if (t < N_EDGES){
    int uu = ei[t], vv = ei[N_EDGES + t];
    int b = uu >> 8;
    int r = uu & 255;
    int c = vv & 255;
    atomicOr(&bm[(size_t)b * 2048 + r * 8 + (c >> 5)], 1u << (c & 31));
  } else {
    int i = t - N_EDGES;
    if (i < N_NODES){
      int b = i >> 8; int p = i & 255;
      atomicOr(&bm[(size_t)b * 2048 + p * 8 + (p >> 5)], 1u << (p & 31));
    }
  }
}

// ==================== fused per-graph kernel ====================
__global__ __launch_bounds__(1024) void k_graph(
    const unsigned* __restrict__ bm,
    const float* __restrict__ src, const float* __restrict__ tgt,
    float* __restrict__ err_ws, float* __restrict__ wd_ws)
{
  __shared__ float          cs[CAPX];
  __shared__ unsigned short ents[CAPX];
  __shared__ unsigned short cidx[CAPX];
  __shared__ int            rp[257], cp[257];
  __shared__ float          su[256], sv[256];
  __shared__ float          sErr[MAXIT], sWd[MAXIT];
  extern __shared__ char    dyn[];
  uint2*    tgtb   = (uint2*)dyn;
  unsigned* m      = (unsigned*)dyn;               // phase-A alias
  unsigned* mT     = (unsigned*)(dyn + 8192);      // phase-A alias (transposed)
  int*      rowpref= (int*)(dyn + 16384);          // phase-A alias
  float*    strip  = (float*)dyn;                  // spill alias

  int g = blockIdx.x, tid = threadIdx.x;
  int lane = tid & 63, wid = tid >> 6;

  // ---------- Phase A: structure (wave-native) ----------
  for (int i = tid; i < 2048; i += 1024) m[i] = bm[(size_t)g * 2048 + i];
  __syncthreads();

  // A1: transpose 256x256 bitmask via ballot
  {
    int R = wid >> 2, C = wid & 3;
    int row = R * 64 + lane;
    uint2 wp = *reinterpret_cast<const uint2*>(&m[row * 8 + C * 2]);
    unsigned long long colbits = (unsigned long long)wp.x |
                                 ((unsigned long long)wp.y << 32);
    unsigned long long mybal = 0;
    for (int c2 = 0; c2 < 64; c2++){
      unsigned long long bal = __ballot((colbits & 1ull) != 0);
      colbits >>= 1;
      if (lane == c2) mybal = bal;
    }
    int col = C * 64 + lane;
    mT[col * 8 + R * 2]     = (unsigned)mybal;
    mT[col * 8 + R * 2 + 1] = (unsigned)(mybal >> 32);
  }
  __syncthreads();

  // A2: rp scan (wave 0) and cp scan (wave 1)
  if (wid < 2){
    const uint4* W4 = reinterpret_cast<const uint4*>(wid == 0 ? m : mT);
    int* out = (wid == 0) ? rp : cp;
    int r0 = lane * 4;
    int s[4];
    #pragma unroll
    for (int j = 0; j < 4; j++){
      uint4 a = W4[(r0 + j) * 2], b = W4[(r0 + j) * 2 + 1];
      s[j] = __popc(a.x) + __popc(a.y) + __popc(a.z) + __popc(a.w) +
             __popc(b.x) + __popc(b.y) + __popc(b.z) + __popc(b.w);
    }
    int tot = s[0] + s[1] + s[2] + s[3];
    int incl = dppScanAdd64(tot);
    int base = incl - tot;
    out[r0]     = base;
    out[r0 + 1] = base + s[0];
    out[r0 + 2] = base + s[0] + s[1];
    out[r0 + 3] = base + s[0] + s[1] + s[2];
    if (lane == 63) out[256] = (incl > CAPX ? CAPX : incl);
  }
  __syncthreads();

  // A3: ents build + rowpref
  if (tid < 256){
    int r = tid, k = rp[r];
    #pragma unroll
    for (int w = 0; w < 8; w++){
      rowpref[r * 8 + w] = k;
      unsigned bits = m[r * 8 + w];
      while (bits){
        int b = __ffs(bits) - 1; bits &= bits - 1;
        if (k < CAPX) ents[k] = (unsigned short)((r << 8) | (w * 32 + b));
        k++;
      }
    }
  }
  __syncthreads();

  // A4: CSC index list
  if (tid < 256){
    int c = tid;
    int cw2 = c >> 5; unsigned cb2 = 1u << (c & 31);
    int kk = cp[c];
    #pragma unroll
    for (int w = 0; w < 8; w++){
      unsigned bits = mT[c * 8 + w];
      while (bits){
        int b = __ffs(bits) - 1; bits &= bits - 1;
        int r = w * 32 + b;
        int idx = rowpref[r * 8 + cw2] + __popc(m[r * 8 + cw2] & (cb2 - 1u));
        if (kk < CAPX && idx < CAPX) cidx[kk] = (unsigned short)idx;
        kk++;
      }
    }
  }
  __syncthreads();   // m/mT/rowpref dead; tgtb region free

  // ---------- Phase B: tgt -> normalized bf16 in LDS (6-bit swizzle, R20) ----------
  const float4* tbase = reinterpret_cast<const float4*>(tgt + (size_t)g * NPG * D_FEAT);
  const float4* sbase = reinterpret_cast<const float4*>(src + (size_t)g * NPG * D_FEAT);
  for (int r = wid; r < 256; r += 16){
    float4 x = tbase[r * 64 + lane];
    float s = x.x*x.x + x.y*x.y + x.z*x.z + x.w*x.w;
    float inv = 1.0f / (sqrtf(bcast63(dppSum64(s))) + 1e-12f);
    unsigned p0 = bf16r(x.x * inv) | (bf16r(x.y * inv) << 16);
    unsigned p1 = bf16r(x.z * inv) | (bf16r(x.w * inv) << 16);
    tgtb[r * 64 + (lane ^ (r & 7) ^ (((r >> 3) & 7) << 3))] = make_uint2(p0, p1);
  }
  __syncthreads();

  // ---------- Phase C: dense cosine via MFMA (R20) ----------
  int G = lane >> 4;
  int l7 = lane & 7;
  int l3 = (lane >> 3) & 1;
  int myrow = wid * 16 + (lane & 15);
  const float4* srow = sbase + myrow * 64;

  float4 a0r[8], a1r[8];
  float ss = 0.f;
  #pragma unroll
  for (int kk = 0; kk < 8; kk++){
    a0r[kk] = srow[kk * 8 + G];
    a1r[kk] = srow[kk * 8 + G + 4];
    ss += a0r[kk].x*a0r[kk].x + a0r[kk].y*a0r[kk].y
        + a0r[kk].z*a0r[kk].z + a0r[kk].w*a0r[kk].w
        + a1r[kk].x*a1r[kk].x + a1r[kk].y*a1r[kk].y
        + a1r[kk].z*a1r[kk].z + a1r[kk].w*a1r[kk].w;
  }
  ss += __shfl_xor(ss, 16);
  ss += __shfl_xor(ss, 32);
  float is = 1.0f / (sqrtf(ss) + 1e-12f);

  U8 af[8];
  #pragma unroll
  for (int kk = 0; kk < 8; kk++){
    af[kk].u[0] = bf16r(a0r[kk].x * is) | (bf16r(a0r[kk].y * is) << 16);
    af[kk].u[1] = bf16r(a0r[kk].z * is) | (bf16r(a0r[kk].w * is) << 16);
    af[kk].u[2] = bf16r(a1r[kk].x * is) | (bf16r(a1r[kk].y * is) << 16);
    af[kk].u[3] = bf16r(a1r[kk].z * is) | (bf16r(a1r[kk].w * is) << 16);
  }

  f32x4 acc[16];
  #pragma unroll
  for (int nt = 0; nt < 16; nt++) acc[nt] = (f32x4){0.f, 0.f, 0.f, 0.f};

  int off0 = (G ^ l7) << 3;
  int off1 = ((G + 4) ^ l7) << 3;
  #pragma unroll
  for (int nt = 0; nt < 16; nt++){
    int n = nt * 16 + (lane & 15);
    int rowbyte = n << 9;
    int khi = (nt * 2 + l3) & 7;
    f32x4 a = acc[nt];
    #pragma unroll
    for (int kk = 0; kk < 8; kk++){
      int gr = (kk ^ khi) << 6;
      uint2 b0 = *reinterpret_cast<const uint2*>(dyn + rowbyte + gr + off0);
      uint2 b1 = *reinterpret_cast<const uint2*>(dyn + rowbyte + gr + off1);
      U8 bf;
      bf.u[0] = b0.x; bf.u[1] = b0.y; bf.u[2] = b1.x; bf.u[3] = b1.y;
      a = __builtin_amdgcn_mfma_f32_16x16x32_bf16(af[kk].v, bf.v, a, 0, 0, 0);
    }
    acc[nt] = a;
  }
  __syncthreads();   // tgtb dead -> strip region free

  // ---------- spill strips + gather support entries ----------
  int total = rp[256];
  int half_end = rp[128];
  if (wid < 8){
    #pragma unroll
    for (int nt = 0; nt < 16; nt++){
      #pragma unroll
      for (int reg = 0; reg < 4; reg++){
        int rl = wid * 16 + G * 4 + reg;
        strip[rl * 256 + nt * 16 + (lane & 15)] = acc[nt][reg];
      }
    }
  }
  __syncthreads();
  for (int e = tid; e < half_end; e += 1024){
    int r = ents[e] >> 8, c = ents[e] & 255;
    cs[e] = (1.0f - strip[r * 256 + c]) * CSCALE;
  }
  __syncthreads();
  if (wid >= 8){
    #pragma unroll
    for (int nt = 0; nt < 16; nt++){
      #pragma unroll
      for (int reg = 0; reg < 4; reg++){
        int rl = (wid - 8) * 16 + G * 4 + reg;
        strip[rl * 256 + nt * 16 + (lane & 15)] = acc[nt][reg];
      }
    }
  }
  __syncthreads();
  for (int e = half_end + tid; e < total; e += 1024){
    int r = (ents[e] >> 8) - 128, c = ents[e] & 255;
    cs[e] = (1.0f - strip[r * 256 + c]) * CSCALE;
  }
  __syncthreads();   // LAST barrier; waves 1..15 exit below

  // ---------- Phase D: single-wave Sinkhorn, ZERO barriers ----------
  if (wid != 0) return;

  // lane owns rows lane, lane+64, lane+128, lane+192 (4 rows, KROW slots each)
  int rsA[4], reA[4], csA[4], ceA[4];
  #pragma unroll
  for (int i = 0; i < 4; i++){
    int r = lane + i * 64;
    rsA[i] = rp[r];  reA[i] = rp[r + 1];
    csA[i] = cp[r];  ceA[i] = cp[r + 1];
  }

  float rw[4 * KROW], rc2[4 * KROW], cwv[4 * KROW];
  unsigned rofs[2 * KROW], cofs[2 * KROW];   // packed pairs of byte offsets
  #pragma unroll
  for (int s = 0; s < 4 * KROW; s++){
    int i = s / KROW, k = s % KROW;
    int idx = rsA[i] + k;
    bool v = idx < reA[i];
    int ai = v ? idx : 0;
    int col = v ? (ents[ai] & 255) : 0;
    float c2 = v ? cs[ai] : 0.f;
    rw[s]  = v ? exp2f(-c2) : 0.f;
    rc2[s] = c2;
    unsigned o = (unsigned)(col * 4);
    if (s & 1) rofs[s >> 1] |= o << 16; else rofs[s >> 1] = o;
  }
  #pragma unroll
  for (int s = 0; s < 4 * KROW; s++){
    int i = s / KROW, k = s % KROW;
    int idx = csA[i] + k;
    bool v = idx < ceA[i];
    int ai = v ? idx : 0;
    int e = v ? (int)cidx[ai] : 0;
    int r2 = v ? (ents[e] >> 8) : 0;
    cwv[s] = v ? exp2f(-cs[e]) : 0.f;
    unsigned o = (unsigned)(r2 * 4);
    if (s & 1) cofs[s >> 1] |= o << 16; else cofs[s >> 1] = o;
  }

  // init scaling vectors (whole wave covers all 256 rows)
  #pragma unroll
  for (int i = 0; i < 4; i++){ su[lane + i * 64] = 1.f; sv[lane + i * 64] = 1.f; }

  const float LOG2_MU = log2f(MU_VAL);
  float aA[4]  = {0.f, 0.f, 0.f, 0.f};
  float ApA[4] = {1.f, 1.f, 1.f, 1.f};
  const char* svB = (const char*)sv;
  const char* suB = (const char*)su;

  for (int it = 0; it < MAXIT; ++it){
    // ---- row pass ----
    float sm[4] = {0.f, 0.f, 0.f, 0.f};
    float wsm[4] = {0.f, 0.f, 0.f, 0.f};
    #pragma unroll
    for (int p = 0; p < 2 * KROW; p++){
      unsigned pk = rofs[p];
      int s0 = 2 * p, s1 = 2 * p + 1;
      float v0 = *reinterpret_cast<const float*>(svB + (pk & 0xFFFFu));
      float v1 = *reinterpret_cast<const float*>(svB + (pk >> 16));
      float x0 = v0 * rw[s0];
      float x1 = v1 * rw[s1];
      sm[s0 / KROW]  += x0 + x1;
      wsm[s0 / KROW] += x0 * rc2[s0] + x1 * rc2[s1];
    }
    #pragma unroll
    for (int i = 0; i < 4; i++){
      for (int idx = rsA[i] + KROW; idx < reA[i]; idx++){   // rare overflow
        float cv = cs[idx];
        float xo = sv[ents[idx] & 255] * exp2f(-cv);
        sm[i] += xo; wsm[i] += xo * cv;
      }
    }
    float errAcc = 0.f, wdAcc = 0.f;
    #pragma unroll
    for (int i = 0; i < 4; i++){
      float An = MU_VAL * __builtin_amdgcn_rcpf(sm[i]);
      float an = LOG2_MU - __builtin_amdgcn_logf(sm[i]);
      su[lane + i * 64] = An;
      errAcc += fabsf(an - aA[i]);
      wdAcc  += ApA[i] * wsm[i];      // wd contribution of iter it-1
      aA[i] = an; ApA[i] = An;
    }
    errAcc = dppSum64(errAcc);
    wdAcc  = dppSum64(wdAcc);
    if (lane == 63){
      sErr[it] = errAcc * (EPSF * LN2_F);
      if (it > 0) sWd[it - 1] = wdAcc * (EPSF * LN2_F);
    }

    // ---- col pass (reads NEW su; wave-lockstep, no barrier) ----
    float cm[4] = {0.f, 0.f, 0.f, 0.f};
    #pragma unroll
    for (int p = 0; p < 2 * KROW; p++){
      unsigned pk = cofs[p];
      int s0 = 2 * p, s1 = 2 * p + 1;
      float v0 = *reinterpret_cast<const float*>(suB + (pk & 0xFFFFu));
      float v1 = *reinterpret_cast<const float*>(suB + (pk >> 16));
      cm[s0 / KROW] += v0 * cwv[s0] + v1 * cwv[s1];
    }
    #pragma unroll
    for (int i = 0; i < 4; i++){
      for (int idx = csA[i] + KROW; idx < ceA[i]; idx++){   // rare overflow
        int e = cidx[idx];
        cm[i] += su[ents[e] >> 8] * exp2f(-cs[e]);
      }
    }
    #pragma unroll
    for (int i = 0; i < 4; i++)
      sv[lane + i * 64] = MU_VAL * __builtin_amdgcn_rcpf(cm[i]);
  }

  // ---- epilogue: wd for the final iteration ----
  {
    float wsm[4] = {0.f, 0.f, 0.f, 0.f};
    #pragma unroll
    for (int p = 0; p < 2 * KROW; p++){
      unsigned pk = rofs[p];
      int s0 = 2 * p, s1 = 2 * p + 1;
      float v0 = *reinterpret_cast<const float*>(svB + (pk & 0xFFFFu));
      float v1 = *reinterpret_cast<const float*>(svB + (pk >> 16));
      wsm[s0 / KROW] += v0 * rw[s0] * rc2[s0] + v1 * rw[s1] * rc2[s1];
    }
    #pragma unroll
    for (int i = 0; i < 4; i++){
      for (int idx = rsA[i] + KROW; idx < reA[i]; idx++){
        float cv = cs[idx];
        wsm[i] += sv[ents[idx] & 255] * exp2f(-cv) * cv;
      }
    }
    float wdAcc = 0.f;
    #pragma unroll
    for (int i = 0; i < 4; i++) wdAcc += ApA[i] * wsm[i];
    wdAcc = dppSum64(wdAcc);
    if (lane == 63) sWd[MAXIT - 1] = wdAcc * (EPSF * LN2_F);
  }

  // ---- dump histories (wave 0 only) ----
  for (int it = lane; it < MAXIT; it += 64){
    err_ws[it * N_GRAPHS + g] = sErr[it];
    wd_ws [it * N_GRAPHS + g] = sWd[it];
  }
}

// -------- parallel find-T + final mean (one block, 16 waves) --------
__global__ __launch_bounds__(1024) void k_findT_final(
    const float* __restrict__ err_ws, const float* __restrict__ wd_ws,
    float* __restrict__ out)
{
  __shared__ float sSum[MAXIT];
  __shared__ int Tm1s;
  int tid = threadIdx.x, lane = tid & 63, wid = tid >> 6;
  for (int it = wid; it < MAXIT; it += 16){
    float4 v = *reinterpret_cast<const float4*>(&err_ws[it * N_GRAPHS + lane * 4]);
    float s = v.x + v.y + v.z + v.w;
    s = dppSum64(s);
    if (lane == 63) sSum[it] = s;
  }
  __syncthreads();
  if (tid == 0){
    int t = MAXIT - 1;
    for (int it = 0; it < MAXIT; ++it){
      if (sSum[it] * (1.0f / 256.0f) < 0.1f){ t = it; break; }
    }
    Tm1s = t;
  }
  __syncthreads();
  if (wid == 0){
    float4 v = *reinterpret_cast<const float4*>(&wd_ws[Tm1s * N_GRAPHS + lane * 4]);
    float s = v.x + v.y + v.z + v.w;
    s = dppSum64(s);
    if (lane == 63) out[0] = 0.5f * s / 256.0f;
  }
}

extern "C" void kernel_launch(void* const* d_in, const int* in_sizes, int n_in,
                              void* d_out, int out_size, void* d_ws, size_t ws_size,
                              hipStream_t stream)
{
  const float* src = (const float*)d_in[0];
  const float* tgt = (const float*)d_in[1];
  const int*   ei  = (const int*)d_in[2];

  char* ws = (char*)d_ws;
  size_t off = 0;
  auto alloc = [&](size_t bytes) -> char* {
    char* p = ws + off;
    off += (bytes + 255) & ~(size_t)255;
    return p;
  };
  unsigned* bm     = (unsigned*) alloc((size_t)N_GRAPHS * 2048 * 4);
  float*    err_ws = (float*)    alloc((size_t)MAXIT * N_GRAPHS * 4);
  float*    wd_ws  = (float*)    alloc((size_t)MAXIT * N_GRAPHS * 4);

  (void)hipFuncSetAttribute((const void*)k_graph,
                            hipFuncAttributeMaxDynamicSharedMemorySize,
                            DYN_SIZE);

  (void)hipMemsetAsync(bm, 0, (size_t)N_GRAPHS * 2048 * 4, stream);
  k_scatter<<<(N_EDGES + N_NODES + 255) / 256, 256, 0, stream>>>(ei, bm);
  k_graph<<<N_GRAPHS, 1024, DYN_SIZE, stream>>>(bm, src, tgt, err_ws, wd_ws);
  k_findT_final<<<1, 1024, 0, stream>>>(err_ws, wd_ws, (float*)d_out);
}

// Round 23
// 712.380 us; speedup vs baseline: 2.1864x; 2.1864x over previous
//
#include <hip/hip_runtime.h>

// Problem constants (fixed by reference setup_inputs)
#define N_NODES  65536
#define D_FEAT   256
#define N_GRAPHS 256
#define NPG      256
#define N_EDGES  524288
#define CAPX     2560     // support cap (true max = 2048 edges + 256 diag = 2304)
#define EPSF     0.1f
#define MAXIT    100
#define KROW     12       // register slots per row (single-wave sink); overflow -> LDS
#define LOG2E_F  1.4426950408889634f
#define LN2_F    0.6931471805599453f
#define CSCALE   (10.0f * LOG2E_F)   // C * (1/eps) * log2(e) -> base-2 domain
#define MU_VAL   (1.0f / 256.0f + 1e-8f)

// dynamic LDS region for k_prep (131072 B), time-multiplexed:
//   phase A: m (8 KB) + mT (8 KB) + rowpref (8 KB)
//   phase B/C: tgtb = 256 rows x 512 B bf16, 6-bit XOR granule swizzle (R20)
//   epilogue: strip = 128 rows x 256 f32
#define DYN_SIZE  131072

typedef __attribute__((ext_vector_type(8))) short short8;
typedef __attribute__((ext_vector_type(4))) float f32x4;
union U8 { unsigned u[4]; short8 v; };

template<int CTRL>
__device__ __forceinline__ float fdpp(float x){
  int xi = __float_as_int(x);
  int i = __builtin_amdgcn_update_dpp(xi, xi, CTRL, 0xf, 0xf, true);
  return __int_as_float(i);
}
__device__ __forceinline__ float dppSum64(float x){
  x += fdpp<0x111>(x);
  x += fdpp<0x112>(x);
  x += fdpp<0x114>(x);
  x += fdpp<0x118>(x);
  x += fdpp<0x142>(x);
  x += fdpp<0x143>(x);
  return x;
}
__device__ __forceinline__ float bcast63(float x){
  return __int_as_float(__builtin_amdgcn_readlane(__float_as_int(x), 63));
}

// int DPP with old=0 — for masked scan steps
template<int CTRL, int RMASK>
__device__ __forceinline__ int idpp0(int x){
  return __builtin_amdgcn_update_dpp(0, x, CTRL, RMASK, 0xf, true);
}
__device__ __forceinline__ int dppScanAdd64(int x){
  x += idpp0<0x111, 0xf>(x);
  x += idpp0<0x112, 0xf>(x);
  x += idpp0<0x114, 0xf>(x);
  x += idpp0<0x118, 0xf>(x);
  x += idpp0<0x142, 0xa>(x);
  x += idpp0<0x143, 0xc>(x);
  return x;
}

__device__ __forceinline__ unsigned bf16r(float f){
  unsigned u = __float_as_uint(f);
  return (u + 0x7FFFu + ((u >> 16) & 1u)) >> 16;
}

// -------- scatter edges + diagonal into per-graph bitmask --------
__global__ __launch_bounds__(256) void k_scatter(const int* __restrict__ ei,
                                                 unsigned* __restrict__ bm){
  int t = blockIdx.x * 256 + threadIdx.x;
  if (t < N_EDGES){
    int uu = ei[t], vv = ei[N_EDGES + t];
    int b = uu >> 8;
    int r = uu & 255;
    int c = vv & 255;
    atomicOr(&bm[(size_t)b * 2048 + r * 8 + (c >> 5)], 1u << (c & 31));
  } else {
    int i = t - N_EDGES;
    if (i < N_NODES){
      int b = i >> 8; int p = i & 255;
      atomicOr(&bm[(size_t)b * 2048 + p * 8 + (p >> 5)], 1u << (p & 31));
    }
  }
}

// ==================== k_prep: A + B + C(MFMA) + writeout (R20 phases) ====================
__global__ __launch_bounds__(1024) void k_prep(
    const unsigned* __restrict__ bm,
    const float* __restrict__ src, const float* __restrict__ tgt,
    float* __restrict__ gvals, unsigned short* __restrict__ gents,
    unsigned short* __restrict__ gcidxo, int* __restrict__ grp,
    int* __restrict__ gcp)
{
  __shared__ float          cs[CAPX];
  __shared__ unsigned short ents[CAPX];
  __shared__ unsigned short cidx[CAPX];
  __shared__ int            rp[257], cp[257];
  extern __shared__ char    dyn[];
  uint2*    tgtb   = (uint2*)dyn;
  unsigned* m      = (unsigned*)dyn;               // phase-A alias
  unsigned* mT     = (unsigned*)(dyn + 8192);      // phase-A alias (transposed)
  int*      rowpref= (int*)(dyn + 16384);          // phase-A alias
  float*    strip  = (float*)dyn;                  // spill alias

  int g = blockIdx.x, tid = threadIdx.x;
  int lane = tid & 63, wid = tid >> 6;

  // ---------- Phase A: structure (wave-native) ----------
  for (int i = tid; i < 2048; i += 1024) m[i] = bm[(size_t)g * 2048 + i];
  __syncthreads();

  // A1: transpose 256x256 bitmask via ballot
  {
    int R = wid >> 2, C = wid & 3;
    int row = R * 64 + lane;
    uint2 wp = *reinterpret_cast<const uint2*>(&m[row * 8 + C * 2]);
    unsigned long long colbits = (unsigned long long)wp.x |
                                 ((unsigned long long)wp.y << 32);
    unsigned long long mybal = 0;
    for (int c2 = 0; c2 < 64; c2++){
      unsigned long long bal = __ballot((colbits & 1ull) != 0);
      colbits >>= 1;
      if (lane == c2) mybal = bal;
    }
    int col = C * 64 + lane;
    mT[col * 8 + R * 2]     = (unsigned)mybal;
    mT[col * 8 + R * 2 + 1] = (unsigned)(mybal >> 32);
  }
  __syncthreads();

  // A2: rp scan (wave 0) and cp scan (wave 1)
  if (wid < 2){
    const uint4* W4 = reinterpret_cast<const uint4*>(wid == 0 ? m : mT);
    int* out = (wid == 0) ? rp : cp;
    int r0 = lane * 4;
    int s[4];
    #pragma unroll
    for (int j = 0; j < 4; j++){
      uint4 a = W4[(r0 + j) * 2], b = W4[(r0 + j) * 2 + 1];
      s[j] = __popc(a.x) + __popc(a.y) + __popc(a.z) + __popc(a.w) +
             __popc(b.x) + __popc(b.y) + __popc(b.z) + __popc(b.w);
    }
    int tot = s[0] + s[1] + s[2] + s[3];
    int incl = dppScanAdd64(tot);
    int base = incl - tot;
    out[r0]     = base;
    out[r0 + 1] = base + s[0];
    out[r0 + 2] = base + s[0] + s[1];
    out[r0 + 3] = base + s[0] + s[1] + s[2];
    if (lane == 63) out[256] = (incl > CAPX ? CAPX : incl);
  }
  __syncthreads();

  // A3: ents build + rowpref
  if (tid < 256){
    int r = tid, k = rp[r];
    #pragma unroll
    for (int w = 0; w < 8; w++){
      rowpref[r * 8 + w] = k;
      unsigned bits = m[r * 8 + w];
      while (bits){
        int b = __ffs(bits) - 1; bits &= bits - 1;
        if (k < CAPX) ents[k] = (unsigned short)((r << 8) | (w * 32 + b));
        k++;
      }
    }
  }
  __syncthreads();

  // A4: CSC index list
  if (tid < 256){
    int c = tid;
    int cw2 = c >> 5; unsigned cb2 = 1u << (c & 31);
    int kk = cp[c];
    #pragma unroll
    for (int w = 0; w < 8; w++){
      unsigned bits = mT[c * 8 + w];
      while (bits){
        int b = __ffs(bits) - 1; bits &= bits - 1;
        int r = w * 32 + b;
        int idx = rowpref[r * 8 + cw2] + __popc(m[r * 8 + cw2] & (cb2 - 1u));
        if (kk < CAPX && idx < CAPX) cidx[kk] = (unsigned short)idx;
        kk++;
      }
    }
  }
  __syncthreads();   // m/mT/rowpref dead; tgtb region free

  // ---------- Phase B: tgt -> normalized bf16 in LDS (6-bit swizzle) ----------
  const float4* tbase = reinterpret_cast<const float4*>(tgt + (size_t)g * NPG * D_FEAT);
  const float4* sbase = reinterpret_cast<const float4*>(src + (size_t)g * NPG * D_FEAT);
  for (int r = wid; r < 256; r += 16){
    float4 x = tbase[r * 64 + lane];
    float s = x.x*x.x + x.y*x.y + x.z*x.z + x.w*x.w;
    float inv = 1.0f / (sqrtf(bcast63(dppSum64(s))) + 1e-12f);
    unsigned p0 = bf16r(x.x * inv) | (bf16r(x.y * inv) << 16);
    unsigned p1 = bf16r(x.z * inv) | (bf16r(x.w * inv) << 16);
    tgtb[r * 64 + (lane ^ (r & 7) ^ (((r >> 3) & 7) << 3))] = make_uint2(p0, p1);
  }
  __syncthreads();

  // ---------- Phase C: dense cosine via MFMA (R20) ----------
  int G = lane >> 4;
  int l7 = lane & 7;
  int l3 = (lane >> 3) & 1;
  int myrow = wid * 16 + (lane & 15);
  const float4* srow = sbase + myrow * 64;

  float4 a0r[8], a1r[8];
  float ss = 0.f;
  #pragma unroll
  for (int kk = 0; kk < 8; kk++){
    a0r[kk] = srow[kk * 8 + G];
    a1r[kk] = srow[kk * 8 + G + 4];
    ss += a0r[kk].x*a0r[kk].x + a0r[kk].y*a0r[kk].y
        + a0r[kk].z*a0r[kk].z + a0r[kk].w*a0r[kk].w
        + a1r[kk].x*a1r[kk].x + a1r[kk].y*a1r[kk].y
        + a1r[kk].z*a1r[kk].z + a1r[kk].w*a1r[kk].w;
  }
  ss += __shfl_xor(ss, 16);
  ss += __shfl_xor(ss, 32);
  float is = 1.0f / (sqrtf(ss) + 1e-12f);

  U8 af[8];
  #pragma unroll
  for (int kk = 0; kk < 8; kk++){
    af[kk].u[0] = bf16r(a0r[kk].x * is) | (bf16r(a0r[kk].y * is) << 16);
    af[kk].u[1] = bf16r(a0r[kk].z * is) | (bf16r(a0r[kk].w * is) << 16);
    af[kk].u[2] = bf16r(a1r[kk].x * is) | (bf16r(a1r[kk].y * is) << 16);
    af[kk].u[3] = bf16r(a1r[kk].z * is) | (bf16r(a1r[kk].w * is) << 16);
  }

  f32x4 acc[16];
  #pragma unroll
  for (int nt = 0; nt < 16; nt++) acc[nt] = (f32x4){0.f, 0.f, 0.f, 0.f};

  int off0 = (G ^ l7) << 3;
  int off1 = ((G + 4) ^ l7) << 3;
  #pragma unroll
  for (int nt = 0; nt < 16; nt++){
    int n = nt * 16 + (lane & 15);
    int rowbyte = n << 9;
    int khi = (nt * 2 + l3) & 7;
    f32x4 a = acc[nt];
    #pragma unroll
    for (int kk = 0; kk < 8; kk++){
      int gr = (kk ^ khi) << 6;
      uint2 b0 = *reinterpret_cast<const uint2*>(dyn + rowbyte + gr + off0);
      uint2 b1 = *reinterpret_cast<const uint2*>(dyn + rowbyte + gr + off1);
      U8 bf;
      bf.u[0] = b0.x; bf.u[1] = b0.y; bf.u[2] = b1.x; bf.u[3] = b1.y;
      a = __builtin_amdgcn_mfma_f32_16x16x32_bf16(af[kk].v, bf.v, a, 0, 0, 0);
    }
    acc[nt] = a;
  }
  __syncthreads();   // tgtb dead -> strip region free

  // ---------- spill strips + gather support entries ----------
  int total = rp[256];
  int half_end = rp[128];
  if (wid < 8){
    #pragma unroll
    for (int nt = 0; nt < 16; nt++){
      #pragma unroll
      for (int reg = 0; reg < 4; reg++){
        int rl = wid * 16 + G * 4 + reg;
        strip[rl * 256 + nt * 16 + (lane & 15)] = acc[nt][reg];
      }
    }
  }
  __syncthreads();
  for (int e = tid; e < half_end; e += 1024){
    int r = ents[e] >> 8, c = ents[e] & 255;
    cs[e] = (1.0f - strip[r * 256 + c]) * CSCALE;
  }
  __syncthreads();
  if (wid >= 8){
    #pragma unroll
    for (int nt = 0; nt < 16; nt++){
      #pragma unroll
      for (int reg = 0; reg < 4; reg++){
        int rl = (wid - 8) * 16 + G * 4 + reg;
        strip[rl * 256 + nt * 16 + (lane & 15)] = acc[nt][reg];
      }
    }
  }
  __syncthreads();
  for (int e = half_end + tid; e < total; e += 1024){
    int r = (ents[e] >> 8) - 128, c = ents[e] & 255;
    cs[e] = (1.0f - strip[r * 256 + c]) * CSCALE;
  }
  __syncthreads();

  // ---------- writeout ----------
  size_t base = (size_t)g * CAPX;
  for (int e = tid; e < total; e += 1024){
    gvals[base + e]  = cs[e];
    gents[base + e]  = ents[e];
    gcidxo[base + e] = cidx[e];
  }
  if (tid < 257){
    grp[g * 257 + tid] = rp[tid];
    gcp[g * 257 + tid] = cp[tid];
  }
}

// ==================== k_sinkD: single-wave zero-barrier Sinkhorn ====================
// One wave per graph, __launch_bounds__(64) -> full VGPR budget (no spill,
// fixing R22's failure). D math verbatim from R22 (validated: absmax 0).
__global__ __launch_bounds__(64) void k_sinkD(
    const float* __restrict__ gvals, const unsigned short* __restrict__ gents,
    const unsigned short* __restrict__ gcidxi, const int* __restrict__ grp,
    const int* __restrict__ gcp,
    float* __restrict__ err_ws, float* __restrict__ wd_ws)
{
  __shared__ float          cs[CAPX];
  __shared__ unsigned short ents[CAPX];
  __shared__ unsigned short cidx[CAPX];
  __shared__ int            rp[257], cp[257];
  __shared__ float          su[256], sv[256];
  __shared__ float          sErr[MAXIT], sWd[MAXIT];
  int g = blockIdx.x, lane = threadIdx.x;

  for (int i = lane; i < 257; i += 64){
    rp[i] = grp[g * 257 + i];
    cp[i] = gcp[g * 257 + i];
  }
  int total = rp[256];          // same-wave LDS dep; compiler inserts waits
  size_t base = (size_t)g * CAPX;
  for (int e0 = lane * 4; e0 < total; e0 += 256){
    float4 c4  = *reinterpret_cast<const float4*>(gvals + base + e0);
    ushort4 e4 = *reinterpret_cast<const ushort4*>(gents + base + e0);
    ushort4 i4 = *reinterpret_cast<const ushort4*>(gcidxi + base + e0);
    *reinterpret_cast<float4*>(&cs[e0])    = c4;
    *reinterpret_cast<ushort4*>(&ents[e0]) = e4;
    *reinterpret_cast<ushort4*>(&cidx[e0]) = i4;
  }

  // lane owns rows lane, lane+64, lane+128, lane+192 (4 rows, KROW slots each)
  int rsA[4], reA[4], csA[4], ceA[4];
  #pragma unroll
  for (int i = 0; i < 4; i++){
    int r = lane + i * 64;
    rsA[i] = rp[r];  reA[i] = rp[r + 1];
    csA[i] = cp[r];  ceA[i] = cp[r + 1];
  }

  float rw[4 * KROW], rc2[4 * KROW], cwv[4 * KROW];
  unsigned rofs[2 * KROW], cofs[2 * KROW];   // packed pairs of byte offsets
  #pragma unroll
  for (int s = 0; s < 4 * KROW; s++){
    int i = s / KROW, k = s % KROW;
    int idx = rsA[i] + k;
    bool v = idx < reA[i];
    int ai = v ? idx : 0;
    int col = v ? (ents[ai] & 255) : 0;
    float c2 = v ? cs[ai] : 0.f;
    rw[s]  = v ? exp2f(-c2) : 0.f;
    rc2[s] = c2;
    unsigned o = (unsigned)(col * 4);
    if (s & 1) rofs[s >> 1] |= o << 16; else rofs[s >> 1] = o;
  }
  #pragma unroll
  for (int s = 0; s < 4 * KROW; s++){
    int i = s / KROW, k = s % KROW;
    int idx = csA[i] + k;
    bool v = idx < ceA[i];
    int ai = v ? idx : 0;
    int e = v ? (int)cidx[ai] : 0;
    int r2 = v ? (ents[e] >> 8) : 0;
    cwv[s] = v ? exp2f(-cs[e]) : 0.f;
    unsigned o = (unsigned)(r2 * 4);
    if (s & 1) cofs[s >> 1] |= o << 16; else cofs[s >> 1] = o;
  }

  #pragma unroll
  for (int i = 0; i < 4; i++){ su[lane + i * 64] = 1.f; sv[lane + i * 64] = 1.f; }

  const float LOG2_MU = log2f(MU_VAL);
  float aA[4]  = {0.f, 0.f, 0.f, 0.f};
  float ApA[4] = {1.f, 1.f, 1.f, 1.f};
  const char* svB = (const char*)sv;
  const char* suB = (const char*)su;

  for (int it = 0; it < MAXIT; ++it){
    // ---- row pass ----
    float sm[4] = {0.f, 0.f, 0.f, 0.f};
    float wsm[4] = {0.f, 0.f, 0.f, 0.f};
    #pragma unroll
    for (int p = 0; p < 2 * KROW; p++){
      unsigned pk = rofs[p];
      int s0 = 2 * p, s1 = 2 * p + 1;
      float v0 = *reinterpret_cast<const float*>(svB + (pk & 0xFFFFu));
      float v1 = *reinterpret_cast<const float*>(svB + (pk >> 16));
      float x0 = v0 * rw[s0];
      float x1 = v1 * rw[s1];
      sm[s0 / KROW]  += x0 + x1;
      wsm[s0 / KROW] += x0 * rc2[s0] + x1 * rc2[s1];
    }
    #pragma unroll
    for (int i = 0; i < 4; i++){
      for (int idx = rsA[i] + KROW; idx < reA[i]; idx++){   // rare overflow
        float cv = cs[idx];
        float xo = sv[ents[idx] & 255] * exp2f(-cv);
        sm[i] += xo; wsm[i] += xo * cv;
      }
    }
    float errAcc = 0.f, wdAcc = 0.f;
    #pragma unroll
    for (int i = 0; i < 4; i++){
      float An = MU_VAL * __builtin_amdgcn_rcpf(sm[i]);
      float an = LOG2_MU - __builtin_amdgcn_logf(sm[i]);
      su[lane + i * 64] = An;
      errAcc += fabsf(an - aA[i]);
      wdAcc  += ApA[i] * wsm[i];      // wd contribution of iter it-1
      aA[i] = an; ApA[i] = An;
    }
    errAcc = dppSum64(errAcc);
    wdAcc  = dppSum64(wdAcc);
    if (lane == 63){
      sErr[it] = errAcc * (EPSF * LN2_F);
      if (it > 0) sWd[it - 1] = wdAcc * (EPSF * LN2_F);
    }

    // ---- col pass (reads NEW su; wave-lockstep, no barrier) ----
    float cm[4] = {0.f, 0.f, 0.f, 0.f};
    #pragma unroll
    for (int p = 0; p < 2 * KROW; p++){
      unsigned pk = cofs[p];
      int s0 = 2 * p, s1 = 2 * p + 1;
      float v0 = *reinterpret_cast<const float*>(suB + (pk & 0xFFFFu));
      float v1 = *reinterpret_cast<const float*>(suB + (pk >> 16));
      cm[s0 / KROW] += v0 * cwv[s0] + v1 * cwv[s1];
    }
    #pragma unroll
    for (int i = 0; i < 4; i++){
      for (int idx = csA[i] + KROW; idx < ceA[i]; idx++){   // rare overflow
        int e = cidx[idx];
        cm[i] += su[ents[e] >> 8] * exp2f(-cs[e]);
      }
    }
    #pragma unroll
    for (int i = 0; i < 4; i++)
      sv[lane + i * 64] = MU_VAL * __builtin_amdgcn_rcpf(cm[i]);
  }

  // ---- epilogue: wd for the final iteration ----
  {
    float wsm[4] = {0.f, 0.f, 0.f, 0.f};
    #pragma unroll
    for (int p = 0; p < 2 * KROW; p++){
      unsigned pk = rofs[p];
      int s0 = 2 * p, s1 = 2 * p + 1;
      float v0 = *reinterpret_cast<const float*>(svB + (pk & 0xFFFFu));
      float v1 = *reinterpret_cast<const float*>(svB + (pk >> 16));
      wsm[s0 / KROW] += v0 * rw[s0] * rc2[s0] + v1 * rw[s1] * rc2[s1];
    }
    #pragma unroll
    for (int i = 0; i < 4; i++){
      for (int idx = rsA[i] + KROW; idx < reA[i]; idx++){
        float cv = cs[idx];
        wsm[i] += sv[ents[idx] & 255] * exp2f(-cv) * cv;
      }
    }
    float wdAcc = 0.f;
    #pragma unroll
    for (int i = 0; i < 4; i++) wdAcc += ApA[i] * wsm[i];
    wdAcc = dppSum64(wdAcc);
    if (lane == 63) sWd[MAXIT - 1] = wdAcc * (EPSF * LN2_F);
  }

  // ---- dump histories ----
  for (int it = lane; it < MAXIT; it += 64){
    err_ws[it * N_GRAPHS + g] = sErr[it];
    wd_ws [it * N_GRAPHS + g] = sWd[it];
  }
}

// -------- parallel find-T + final mean (one block, 16 waves) --------
__global__ __launch_bounds__(1024) void k_findT_final(
    const float* __restrict__ err_ws, const float* __restrict__ wd_ws,
    float* __restrict__ out)
{
  __shared__ float sSum[MAXIT];
  __shared__ int Tm1s;
  int tid = threadIdx.x, lane = tid & 63, wid = tid >> 6;
  for (int it = wid; it < MAXIT; it += 16){
    float4 v = *reinterpret_cast<const float4*>(&err_ws[it * N_GRAPHS + lane * 4]);
    float s = v.x + v.y + v.z + v.w;
    s = dppSum64(s);
    if (lane == 63) sSum[it] = s;
  }
  __syncthreads();
  if (tid == 0){
    int t = MAXIT - 1;
    for (int it = 0; it < MAXIT; ++it){
      if (sSum[it] * (1.0f / 256.0f) < 0.1f){ t = it; break; }
    }
    Tm1s = t;
  }
  __syncthreads();
  if (wid == 0){
    float4 v = *reinterpret_cast<const float4*>(&wd_ws[Tm1s * N_GRAPHS + lane * 4]);
    float s = v.x + v.y + v.z + v.w;
    s = dppSum64(s);
    if (lane == 63) out[0] = 0.5f * s / 256.0f;
  }
}

extern "C" void kernel_launch(void* const* d_in, const int* in_sizes, int n_in,
                              void* d_out, int out_size, void* d_ws, size_t ws_size,
                              hipStream_t stream)
{
  const float* src = (const float*)d_in[0];
  const float* tgt = (const float*)d_in[1];
  const int*   ei  = (const int*)d_in[2];

  char* ws = (char*)d_ws;
  size_t off = 0;
  auto alloc = [&](size_t bytes) -> char* {
    char* p = ws + off;
    off += (bytes + 255) & ~(size_t)255;
    return p;
  };
  unsigned*       bm     = (unsigned*)      alloc((size_t)N_GRAPHS * 2048 * 4);
  float*          gvals  = (float*)         alloc((size_t)N_GRAPHS * CAPX * 4);
  unsigned short* gents  = (unsigned short*)alloc((size_t)N_GRAPHS * CAPX * 2);
  unsigned short* gcidx  = (unsigned short*)alloc((size_t)N_GRAPHS * CAPX * 2);
  int*            grp    = (int*)           alloc((size_t)N_GRAPHS * 257 * 4);
  int*            gcp    = (int*)           alloc((size_t)N_GRAPHS * 257 * 4);
  float*          err_ws = (float*)         alloc((size_t)MAXIT * N_GRAPHS * 4);
  float*          wd_ws  = (float*)         alloc((size_t)MAXIT * N_GRAPHS * 4);

  (void)hipFuncSetAttribute((const void*)k_prep,
                            hipFuncAttributeMaxDynamicSharedMemorySize,
                            DYN_SIZE);

  (void)hipMemsetAsync(bm, 0, (size_t)N_GRAPHS * 2048 * 4, stream);
  k_scatter<<<(N_EDGES + N_NODES + 255) / 256, 256, 0, stream>>>(ei, bm);
  k_prep<<<N_GRAPHS, 1024, DYN_SIZE, stream>>>(bm, src, tgt, gvals, gents, gcidx,
                                               grp, gcp);
  k_sinkD<<<N_GRAPHS, 64, 0, stream>>>(gvals, gents, gcidx, grp, gcp,
                                       err_ws, wd_ws);
  k_findT_final<<<1, 1024, 0, stream>>>(err_ws, wd_ws, (float*)d_out);
}

// Round 24
// 152.910 us; speedup vs baseline: 10.1861x; 4.6588x over previous
//
#include <hip/hip_runtime.h>

// Problem constants (fixed by reference setup_inputs)
#define N_NODES  65536
#define D_FEAT   256
#define N_GRAPHS 256
#define NPG      256
#define N_EDGES  524288
#define CAPX     2560     // support cap (true max = 2048 edges + 256 diag = 2304)
#define EPSF     0.1f
#define MAXIT    100
#define KMAX     4        // sink register slots per sub-thread; 4 subs -> 16/row
#define LOG2E_F  1.4426950408889634f
#define LN2_F    0.6931471805599453f
#define CSCALE   (10.0f * LOG2E_F)   // C * (1/eps) * log2(e) -> base-2 domain
#define MU_VAL   (1.0f / 256.0f + 1e-8f)

// dynamic LDS region (131072 B), time-multiplexed:
//   phase A: m (8 KB) + mT (8 KB) + rowpref (8 KB)
//   phase B/C: tgtb = 256 rows x 512 B bf16, 6-bit XOR granule swizzle
//   epilogue: strip = 128 rows x 256 f32
#define DYN_SIZE  131072

typedef __attribute__((ext_vector_type(8))) short short8;
typedef __attribute__((ext_vector_type(4))) float f32x4;
union U8 { unsigned u[4]; short8 v; };

template<int CTRL>
__device__ __forceinline__ float fdpp(float x){
  int xi = __float_as_int(x);
  int i = __builtin_amdgcn_update_dpp(xi, xi, CTRL, 0xf, 0xf, true);
  return __int_as_float(i);
}
__device__ __forceinline__ float dppSum64(float x){
  x += fdpp<0x111>(x);
  x += fdpp<0x112>(x);
  x += fdpp<0x114>(x);
  x += fdpp<0x118>(x);
  x += fdpp<0x142>(x);
  x += fdpp<0x143>(x);
  return x;
}
__device__ __forceinline__ float bcast63(float x){
  return __int_as_float(__builtin_amdgcn_readlane(__float_as_int(x), 63));
}
#define QXOR1 0xB1
#define QXOR2 0x4E

// int DPP with old=0 — for masked scan steps
template<int CTRL, int RMASK>
__device__ __forceinline__ int idpp0(int x){
  return __builtin_amdgcn_update_dpp(0, x, CTRL, RMASK, 0xf, true);
}
// wave64 inclusive scan (masked row_bcast idiom)
__device__ __forceinline__ int dppScanAdd64(int x){
  x += idpp0<0x111, 0xf>(x);
  x += idpp0<0x112, 0xf>(x);
  x += idpp0<0x114, 0xf>(x);
  x += idpp0<0x118, 0xf>(x);
  x += idpp0<0x142, 0xa>(x);
  x += idpp0<0x143, 0xc>(x);
  return x;
}

__device__ __forceinline__ unsigned bf16r(float f){
  unsigned u = __float_as_uint(f);
  return (u + 0x7FFFu + ((u >> 16) & 1u)) >> 16;
}

// -------- scatter edges + diagonal into per-graph bitmask --------
__global__ __launch_bounds__(256) void k_scatter(const int* __restrict__ ei,
                                                 unsigned* __restrict__ bm){
  int t = blockIdx.x * 256 + threadIdx.x;
  if (t < N_EDGES){
    int uu = ei[t], vv = ei[N_EDGES + t];
    int b = uu >> 8;
    int r = uu & 255;
    int c = vv & 255;
    atomicOr(&bm[(size_t)b * 2048 + r * 8 + (c >> 5)], 1u << (c & 31));
  } else {
    int i = t - N_EDGES;
    if (i < N_NODES){
      int b = i >> 8; int p = i & 255;
      atomicOr(&bm[(size_t)b * 2048 + p * 8 + (p >> 5)], 1u << (p & 31));
    }
  }
}

// ==================== fused per-graph kernel ====================
__global__ __launch_bounds__(1024) void k_graph(
    const unsigned* __restrict__ bm,
    const float* __restrict__ src, const float* __restrict__ tgt,
    float* __restrict__ err_ws, float* __restrict__ wd_ws)
{
  __shared__ float          cs[CAPX];
  __shared__ unsigned short ents[CAPX];
  __shared__ unsigned short cidx[CAPX];
  __shared__ int            rp[257], cp[257];
  __shared__ float          su[256], sv[256], drow[256], wrow[256];
  __shared__ float          sErr[MAXIT], sWd[MAXIT];
  extern __shared__ char    dyn[];
  uint2*    tgtb   = (uint2*)dyn;
  unsigned* m      = (unsigned*)dyn;               // phase-A alias
  unsigned* mT     = (unsigned*)(dyn + 8192);      // phase-A alias (transposed)
  int*      rowpref= (int*)(dyn + 16384);          // phase-A alias
  float*    strip  = (float*)dyn;                  // spill alias

  int g = blockIdx.x, tid = threadIdx.x;
  int lane = tid & 63, wid = tid >> 6;

  // ---------- Phase A: structure (wave-native) ----------
  for (int i = tid; i < 2048; i += 1024) m[i] = bm[(size_t)g * 2048 + i];
  __syncthreads();

  // A1: transpose 256x256 bitmask via ballot
  {
    int R = wid >> 2, C = wid & 3;
    int row = R * 64 + lane;
    uint2 wp = *reinterpret_cast<const uint2*>(&m[row * 8 + C * 2]);
    unsigned long long colbits = (unsigned long long)wp.x |
                                 ((unsigned long long)wp.y << 32);
    unsigned long long mybal = 0;
    for (int c2 = 0; c2 < 64; c2++){
      unsigned long long bal = __ballot((colbits & 1ull) != 0);
      colbits >>= 1;
      if (lane == c2) mybal = bal;
    }
    int col = C * 64 + lane;
    mT[col * 8 + R * 2]     = (unsigned)mybal;
    mT[col * 8 + R * 2 + 1] = (unsigned)(mybal >> 32);
  }
  __syncthreads();

  // A2: rp scan (wave 0) and cp scan (wave 1)
  if (wid < 2){
    const uint4* W4 = reinterpret_cast<const uint4*>(wid == 0 ? m : mT);
    int* out = (wid == 0) ? rp : cp;
    int r0 = lane * 4;
    int s[4];
    #pragma unroll
    for (int j = 0; j < 4; j++){
      uint4 a = W4[(r0 + j) * 2], b = W4[(r0 + j) * 2 + 1];
      s[j] = __popc(a.x) + __popc(a.y) + __popc(a.z) + __popc(a.w) +
             __popc(b.x) + __popc(b.y) + __popc(b.z) + __popc(b.w);
    }
    int tot = s[0] + s[1] + s[2] + s[3];
    int incl = dppScanAdd64(tot);
    int base = incl - tot;
    out[r0]     = base;
    out[r0 + 1] = base + s[0];
    out[r0 + 2] = base + s[0] + s[1];
    out[r0 + 3] = base + s[0] + s[1] + s[2];
    if (lane == 63) out[256] = (incl > CAPX ? CAPX : incl);
  }
  __syncthreads();

  // A3: ents build + rowpref
  if (tid < 256){
    int r = tid, k = rp[r];
    #pragma unroll
    for (int w = 0; w < 8; w++){
      rowpref[r * 8 + w] = k;
      unsigned bits = m[r * 8 + w];
      while (bits){
        int b = __ffs(bits) - 1; bits &= bits - 1;
        if (k < CAPX) ents[k] = (unsigned short)((r << 8) | (w * 32 + b));
        k++;
      }
    }
  }
  __syncthreads();

  // A4: CSC index list
  if (tid < 256){
    int c = tid;
    int cw2 = c >> 5; unsigned cb2 = 1u << (c & 31);
    int kk = cp[c];
    #pragma unroll
    for (int w = 0; w < 8; w++){
      unsigned bits = mT[c * 8 + w];
      while (bits){
        int b = __ffs(bits) - 1; bits &= bits - 1;
        int r = w * 32 + b;
        int idx = rowpref[r * 8 + cw2] + __popc(m[r * 8 + cw2] & (cb2 - 1u));
        if (kk < CAPX && idx < CAPX) cidx[kk] = (unsigned short)idx;
        kk++;
      }
    }
  }
  __syncthreads();   // m/mT/rowpref dead; tgtb region free

  // ---------- Phase B: tgt -> normalized bf16 in LDS (6-bit swizzle) ----------
  const float4* tbase = reinterpret_cast<const float4*>(tgt + (size_t)g * NPG * D_FEAT);
  const float4* sbase = reinterpret_cast<const float4*>(src + (size_t)g * NPG * D_FEAT);
  for (int r = wid; r < 256; r += 16){
    float4 x = tbase[r * 64 + lane];
    float s = x.x*x.x + x.y*x.y + x.z*x.z + x.w*x.w;
    float inv = 1.0f / (sqrtf(bcast63(dppSum64(s))) + 1e-12f);
    unsigned p0 = bf16r(x.x * inv) | (bf16r(x.y * inv) << 16);
    unsigned p1 = bf16r(x.z * inv) | (bf16r(x.w * inv) << 16);
    tgtb[r * 64 + (lane ^ (r & 7) ^ (((r >> 3) & 7) << 3))] = make_uint2(p0, p1);
  }
  __syncthreads();

  // ---------- Phase C: dense cosine via MFMA ----------
  // src row register-cached across norm pass and fragment pass (one read).
  int G = lane >> 4;
  int l7 = lane & 7;
  int l3 = (lane >> 3) & 1;
  int myrow = wid * 16 + (lane & 15);
  const float4* srow = sbase + myrow * 64;

  float4 a0r[8], a1r[8];
  float ss = 0.f;
  #pragma unroll
  for (int kk = 0; kk < 8; kk++){
    a0r[kk] = srow[kk * 8 + G];
    a1r[kk] = srow[kk * 8 + G + 4];
    ss += a0r[kk].x*a0r[kk].x + a0r[kk].y*a0r[kk].y
        + a0r[kk].z*a0r[kk].z + a0r[kk].w*a0r[kk].w
        + a1r[kk].x*a1r[kk].x + a1r[kk].y*a1r[kk].y
        + a1r[kk].z*a1r[kk].z + a1r[kk].w*a1r[kk].w;
  }
  ss += __shfl_xor(ss, 16);
  ss += __shfl_xor(ss, 32);
  float is = 1.0f / (sqrtf(ss) + 1e-12f);

  U8 af[8];
  #pragma unroll
  for (int kk = 0; kk < 8; kk++){
    af[kk].u[0] = bf16r(a0r[kk].x * is) | (bf16r(a0r[kk].y * is) << 16);
    af[kk].u[1] = bf16r(a0r[kk].z * is) | (bf16r(a0r[kk].w * is) << 16);
    af[kk].u[2] = bf16r(a1r[kk].x * is) | (bf16r(a1r[kk].y * is) << 16);
    af[kk].u[3] = bf16r(a1r[kk].z * is) | (bf16r(a1r[kk].w * is) << 16);
  }

  f32x4 acc[16];
  #pragma unroll
  for (int nt = 0; nt < 16; nt++) acc[nt] = (f32x4){0.f, 0.f, 0.f, 0.f};

  int off0 = (G ^ l7) << 3;
  int off1 = ((G + 4) ^ l7) << 3;
  #pragma unroll
  for (int nt = 0; nt < 16; nt++){
    int n = nt * 16 + (lane & 15);
    int rowbyte = n << 9;
    int khi = (nt * 2 + l3) & 7;
    f32x4 a = acc[nt];
    #pragma unroll
    for (int kk = 0; kk < 8; kk++){
      int gr = (kk ^ khi) << 6;
      uint2 b0 = *reinterpret_cast<const uint2*>(dyn + rowbyte + gr + off0);
      uint2 b1 = *reinterpret_cast<const uint2*>(dyn + rowbyte + gr + off1);
      U8 bf;
      bf.u[0] = b0.x; bf.u[1] = b0.y; bf.u[2] = b1.x; bf.u[3] = b1.y;
      a = __builtin_amdgcn_mfma_f32_16x16x32_bf16(af[kk].v, bf.v, a, 0, 0, 0);
    }
    acc[nt] = a;
  }
  __syncthreads();   // tgtb dead -> strip region free

  // ---------- spill strips + gather support entries ----------
  int total = rp[256];
  int half_end = rp[128];
  if (wid < 8){
    #pragma unroll
    for (int nt = 0; nt < 16; nt++){
      #pragma unroll
      for (int reg = 0; reg < 4; reg++){
        int rl = wid * 16 + G * 4 + reg;
        strip[rl * 256 + nt * 16 + (lane & 15)] = acc[nt][reg];
      }
    }
  }
  __syncthreads();
  for (int e = tid; e < half_end; e += 1024){
    int r = ents[e] >> 8, c = ents[e] & 255;
    cs[e] = (1.0f - strip[r * 256 + c]) * CSCALE;
  }
  __syncthreads();
  if (wid >= 8){
    #pragma unroll
    for (int nt = 0; nt < 16; nt++){
      #pragma unroll
      for (int reg = 0; reg < 4; reg++){
        int rl = (wid - 8) * 16 + G * 4 + reg;
        strip[rl * 256 + nt * 16 + (lane & 15)] = acc[nt][reg];
      }
    }
  }
  __syncthreads();
  for (int e = half_end + tid; e < total; e += 1024){
    int r = (ents[e] >> 8) - 128, c = ents[e] & 255;
    cs[e] = (1.0f - strip[r * 256 + c]) * CSCALE;
  }
  __syncthreads();

  // ---------- Phase D: Sinkhorn (multiplicative domain) ----------
  int row = tid >> 2, sub = tid & 3;

  int rs = rp[row], re = rp[row + 1];
  int rcol[KMAX]; float rw[KMAX], rc2[KMAX];
  #pragma unroll
  for (int k = 0; k < KMAX; k++){
    int idx = rs + sub + 4 * k;
    bool v = idx < re;
    int ai = v ? idx : 0;
    rcol[k] = v ? (ents[ai] & 255) : 0;
    float c2 = v ? cs[ai] : 0.f;
    rw[k]  = v ? exp2f(-c2) : 0.f;
    rc2[k] = c2;
  }
  int rOv = rs + sub + 4 * KMAX;

  int cs0 = cp[row], ce = cp[row + 1];
  int crow[KMAX]; float cw[KMAX];
  #pragma unroll
  for (int k = 0; k < KMAX; k++){
    int idx = cs0 + sub + 4 * k;
    bool v = idx < ce;
    int ai = v ? idx : 0;
    int e = v ? (int)cidx[ai] : 0;
    crow[k] = v ? (ents[e] >> 8) : 0;
    cw[k]   = v ? exp2f(-cs[e]) : 0.f;
  }
  int cOv = cs0 + sub + 4 * KMAX;

  if (tid < 256){ su[tid] = 1.f; sv[tid] = 1.f; }
  __syncthreads();

  const float LOG2_MU = log2f(MU_VAL);
  float a = 0.f, Aprev = 1.f;

  for (int it = 0; it < MAXIT; ++it){
    float x0 = sv[rcol[0]] * rw[0];
    float x1 = sv[rcol[1]] * rw[1];
    float x2 = sv[rcol[2]] * rw[2];
    float x3 = sv[rcol[3]] * rw[3];
    float sm   = x0 + x1 + x2 + x3;
    float wsum = x0*rc2[0] + x1*rc2[1] + x2*rc2[2] + x3*rc2[3];
    for (int idx = rOv; idx < re; idx += 4){
      float cv = cs[idx];
      float xo = sv[ents[idx] & 255] * exp2f(-cv);
      sm += xo; wsum += xo * cv;
    }
    sm   += fdpp<QXOR1>(sm);   sm   += fdpp<QXOR2>(sm);
    wsum += fdpp<QXOR1>(wsum); wsum += fdpp<QXOR2>(wsum);
    float Anew = MU_VAL * __builtin_amdgcn_rcpf(sm);
    float an   = LOG2_MU - __builtin_amdgcn_logf(sm);
    if (sub == 0){
      su[row]   = Anew;
      drow[row] = fabsf(an - a);
      wrow[row] = Aprev * wsum;
    }
    a = an; Aprev = Anew;
    __syncthreads();

    if (tid < 64){
      float e4 = drow[tid] + drow[tid + 64] + drow[tid + 128] + drow[tid + 192];
      e4 = dppSum64(e4);
      if (lane == 63) sErr[it] = e4 * (EPSF * LN2_F);
    } else if (tid < 128 && it > 0){
      int l = tid - 64;
      float w4 = wrow[l] + wrow[l + 64] + wrow[l + 128] + wrow[l + 192];
      w4 = dppSum64(w4);
      if (lane == 63) sWd[it - 1] = w4 * (EPSF * LN2_F);
    }

    float y0 = su[crow[0]] * cw[0];
    float y1 = su[crow[1]] * cw[1];
    float y2 = su[crow[2]] * cw[2];
    float y3 = su[crow[3]] * cw[3];
    float csm = y0 + y1 + y2 + y3;
    for (int idx = cOv; idx < ce; idx += 4){
      int e = cidx[idx];
      csm += su[ents[e] >> 8] * exp2f(-cs[e]);
    }
    csm += fdpp<QXOR1>(csm); csm += fdpp<QXOR2>(csm);
    float Bnew = MU_VAL * __builtin_amdgcn_rcpf(csm);
    if (sub == 0) sv[row] = Bnew;
    __syncthreads();
  }

  {
    float x0 = sv[rcol[0]] * rw[0];
    float x1 = sv[rcol[1]] * rw[1];
    float x2 = sv[rcol[2]] * rw[2];
    float x3 = sv[rcol[3]] * rw[3];
    float wsum = x0*rc2[0] + x1*rc2[1] + x2*rc2[2] + x3*rc2[3];
    for (int idx = rOv; idx < re; idx += 4){
      float cv = cs[idx];
      wsum += sv[ents[idx] & 255] * exp2f(-cv) * cv;
    }
    wsum += fdpp<QXOR1>(wsum); wsum += fdpp<QXOR2>(wsum);
    if (sub == 0) wrow[row] = Aprev * wsum;
    __syncthreads();
    if (tid < 64){
      float w4 = wrow[tid] + wrow[tid + 64] + wrow[tid + 128] + wrow[tid + 192];
      w4 = dppSum64(w4);
      if (lane == 63) sWd[MAXIT - 1] = w4 * (EPSF * LN2_F);
    }
    __syncthreads();
  }

  for (int it = tid; it < MAXIT; it += 1024){
    err_ws[it * N_GRAPHS + g] = sErr[it];
    wd_ws [it * N_GRAPHS + g] = sWd[it];
  }
}

// -------- parallel find-T + final mean (one block, 16 waves) --------
__global__ __launch_bounds__(1024) void k_findT_final(
    const float* __restrict__ err_ws, const float* __restrict__ wd_ws,
    float* __restrict__ out)
{
  __shared__ float sSum[MAXIT];
  __shared__ int Tm1s;
  int tid = threadIdx.x, lane = tid & 63, wid = tid >> 6;
  for (int it = wid; it < MAXIT; it += 16){
    float4 v = *reinterpret_cast<const float4*>(&err_ws[it * N_GRAPHS + lane * 4]);
    float s = v.x + v.y + v.z + v.w;
    s = dppSum64(s);
    if (lane == 63) sSum[it] = s;
  }
  __syncthreads();
  if (tid == 0){
    int t = MAXIT - 1;
    for (int it = 0; it < MAXIT; ++it){
      if (sSum[it] * (1.0f / 256.0f) < 0.1f){ t = it; break; }
    }
    Tm1s = t;
  }
  __syncthreads();
  if (wid == 0){
    float4 v = *reinterpret_cast<const float4*>(&wd_ws[Tm1s * N_GRAPHS + lane * 4]);
    float s = v.x + v.y + v.z + v.w;
    s = dppSum64(s);
    if (lane == 63) out[0] = 0.5f * s / 256.0f;
  }
}

extern "C" void kernel_launch(void* const* d_in, const int* in_sizes, int n_in,
                              void* d_out, int out_size, void* d_ws, size_t ws_size,
                              hipStream_t stream)
{
  const float* src = (const float*)d_in[0];
  const float* tgt = (const float*)d_in[1];
  const int*   ei  = (const int*)d_in[2];

  char* ws = (char*)d_ws;
  size_t off = 0;
  auto alloc = [&](size_t bytes) -> char* {
    char* p = ws + off;
    off += (bytes + 255) & ~(size_t)255;
    return p;
  };
  unsigned* bm     = (unsigned*) alloc((size_t)N_GRAPHS * 2048 * 4);
  float*    err_ws = (float*)    alloc((size_t)MAXIT * N_GRAPHS * 4);
  float*    wd_ws  = (float*)    alloc((size_t)MAXIT * N_GRAPHS * 4);

  (void)hipFuncSetAttribute((const void*)k_graph,
                            hipFuncAttributeMaxDynamicSharedMemorySize,
                            DYN_SIZE);

  (void)hipMemsetAsync(bm, 0, (size_t)N_GRAPHS * 2048 * 4, stream);
  k_scatter<<<(N_EDGES + N_NODES + 255) / 256, 256, 0, stream>>>(ei, bm);
  k_graph<<<N_GRAPHS, 1024, DYN_SIZE, stream>>>(bm, src, tgt, err_ws, wd_ws);
  k_findT_final<<<1, 1024, 0, stream>>>(err_ws, wd_ws, (float*)d_out);
}